// Round 4
// baseline (956.681 us; speedup 1.0000x reference)
//
#include <hip/hip_runtime.h>

// DigitCaps dynamic routing, all-f32, single persistent kernel with hand-rolled
// grid barriers (one counter slot per barrier instance, zeroed by memset).
// Phases per routing iter:
//   P1 gemm1: part[ks] = x(128 rows) @ (c .* Wr); c computed inline from b_ij
//   P2 reduce 128 partials + squash -> v (or out)
//   P3 gemm2+agree: b_ij += 1/512 * sum W .* (x^T v)   (skip on last iter)
// Wr[(i,s),(o,p)] built once in-kernel (P0); b_ij zeroed in P0.

#define IC 1152
#define OC 10
#define PS 16
#define SS 8
#define NB 512
#define KD 9216
#define ND 160

#define GRID 512
#define BLK 256

#define P1_BM 128
#define P1_KSP 72
#define P1_KC 36

#define P3_KT 96
#define P3_NKT 96
#define P3_BCH 32

__device__ __forceinline__ void gbar(unsigned* slot)
{
    __syncthreads();
    if (threadIdx.x == 0) {
        __threadfence(); // device-scope release: flush local XCD L2
        __hip_atomic_fetch_add(slot, 1u, __ATOMIC_RELEASE, __HIP_MEMORY_SCOPE_AGENT);
        while (__hip_atomic_load(slot, __ATOMIC_ACQUIRE, __HIP_MEMORY_SCOPE_AGENT) < (unsigned)GRID)
            __builtin_amdgcn_s_sleep(1);
        __threadfence(); // device-scope acquire: invalidate stale lines
    }
    __syncthreads();
}

__global__ __launch_bounds__(BLK, 2) void digitcaps_mega(const float* __restrict__ x,
                                                         const float* __restrict__ W,
                                                         float* __restrict__ out,
                                                         float* __restrict__ ws)
{
    // smem union: P1 xl[36][132] (19008B) + wl[36][164] (23616B) + cl[96] (384B)
    //             P3 xl3[32][100] (12800B) + vl3[32][164] (20992B)
    __shared__ __align__(16) char smem[43008];
    __shared__ float agr[120];
    __shared__ float sm[344]; // softmax scratch: maxpart[160], sumpart[160], mo[10]@320, inv[10]@330

    float* b_ij = ws;            // 11520
    float* wrb  = ws + 11520;    // 1474560
    float* part = ws + 1486080;  // 128*81920 = 10485760
    float* vbuf = ws + 11971840; // 81920
    unsigned* bar = (unsigned*)(ws + 12053760); // 16 slots (memset 0 by host)

    const int tid = threadIdx.x;
    const int bid = blockIdx.x;
    const int gid = bid * BLK + tid;
    const int cgx = tid & 15, rgx = tid >> 4;
    const int c0 = cgx * 10;

    float (*xl1)[132] = (float (*)[132])smem;
    float (*wl1)[164] = (float (*)[164])(smem + 19008);
    float* cl         = (float*)(smem + 42624);
    float (*xl3)[100] = (float (*)[100])smem;
    float (*vl3)[164] = (float (*)[164])(smem + 12800);

    int slot = 0;

    // ---------------- P0: zero b_ij, build Wr ----------------
    if (gid < IC * OC) b_ij[gid] = 0.f;
    for (int q = gid; q < (KD * ND) / 4; q += GRID * BLK) {
        const int k = q / 40;
        const int n4 = q - k * 40;
        const int i = k >> 3, s = k & 7;
        const int o = n4 >> 2;
        const int p0 = (n4 << 2) & 15;
        const float* wsrc = W + (((size_t)(i * OC + o) * PS) + p0) * SS + s;
        float4 t;
        t.x = wsrc[0]; t.y = wsrc[SS]; t.z = wsrc[2 * SS]; t.w = wsrc[3 * SS];
        *(float4*)(wrb + (size_t)q * 4) = t;
    }
    gbar(&bar[slot++]);

    for (int it = 0; it < 3; ++it) {
        // ---------------- P1: gemm1 split-K, softmax inline ----------------
        {
            const int mb = bid & 3, ks = bid >> 2;
            const int m0 = mb * P1_BM, k0s = ks * P1_KSP;
            const int r0 = rgx * 8;

            if (it == 0) {
                if (tid < 90) cl[tid] = 1.0f / 1152.0f;
            } else {
                // softmax over i per column o, recomputed per block (b_ij is 46KB, L2-hot)
                if (tid < 160) {
                    const int o = tid % 10, seg = tid / 10;
                    const float* bp = b_ij + o;
                    float m = -3.4e38f;
                    for (int i = seg * 72; i < seg * 72 + 72; ++i)
                        m = fmaxf(m, bp[i * 10]);
                    sm[o * 16 + seg] = m;
                }
                __syncthreads();
                if (tid < 10) {
                    float m = sm[tid * 16];
                    for (int s2 = 1; s2 < 16; ++s2) m = fmaxf(m, sm[tid * 16 + s2]);
                    sm[320 + tid] = m;
                }
                __syncthreads();
                if (tid < 160) {
                    const int o = tid % 10, seg = tid / 10;
                    const float mo = sm[320 + o];
                    const float* bp = b_ij + o;
                    float s = 0.f;
                    for (int i = seg * 72; i < seg * 72 + 72; ++i)
                        s += expf(bp[i * 10] - mo);
                    sm[160 + o * 16 + seg] = s;
                }
                __syncthreads();
                if (tid < 10) {
                    float s = 0.f;
                    for (int s2 = 0; s2 < 16; ++s2) s += sm[160 + tid * 16 + s2];
                    sm[330 + tid] = 1.0f / s;
                }
                __syncthreads();
                if (tid < 90) {
                    const int il = tid / 10, o = tid % 10;
                    const int i = ks * 9 + il;
                    cl[tid] = expf(b_ij[i * 10 + o] - sm[320 + o]) * sm[330 + o];
                }
            }
            __syncthreads();

            float acc[8][10] = {};
            for (int kc = 0; kc < P1_KSP; kc += P1_KC) {
                const int k0 = k0s + kc;
                for (int q = tid; q < 1152; q += BLK) {
                    const int r = q / 9, kv4 = q - r * 9;
                    const float4 t = *(const float4*)(x + (size_t)(m0 + r) * KD + k0 + kv4 * 4);
                    xl1[kv4 * 4 + 0][r] = t.x;
                    xl1[kv4 * 4 + 1][r] = t.y;
                    xl1[kv4 * 4 + 2][r] = t.z;
                    xl1[kv4 * 4 + 3][r] = t.w;
                }
                for (int q = tid; q < 1440; q += BLK) {
                    const int rr = q / 40, c4 = q - rr * 40;
                    float4 t = *(const float4*)(wrb + (size_t)(k0 + rr) * ND + c4 * 4);
                    const float sc = cl[(((kc + rr) >> 3) * 10) + (c4 >> 2)];
                    t.x *= sc; t.y *= sc; t.z *= sc; t.w *= sc;
                    *(float4*)&wl1[rr][c4 * 4] = t;
                }
                __syncthreads();
#pragma unroll 4
                for (int kk = 0; kk < P1_KC; ++kk) {
                    const float4 a0 = *(const float4*)&xl1[kk][r0];
                    const float4 a1 = *(const float4*)&xl1[kk][r0 + 4];
                    const float2 w0 = *(const float2*)&wl1[kk][c0 + 0];
                    const float2 w1 = *(const float2*)&wl1[kk][c0 + 2];
                    const float2 w2 = *(const float2*)&wl1[kk][c0 + 4];
                    const float2 w3 = *(const float2*)&wl1[kk][c0 + 6];
                    const float2 w4 = *(const float2*)&wl1[kk][c0 + 8];
                    const float av[8] = { a0.x, a0.y, a0.z, a0.w, a1.x, a1.y, a1.z, a1.w };
                    const float wv[10] = { w0.x, w0.y, w1.x, w1.y, w2.x,
                                           w2.y, w3.x, w3.y, w4.x, w4.y };
#pragma unroll
                    for (int r = 0; r < 8; ++r)
#pragma unroll
                        for (int n = 0; n < 10; ++n)
                            acc[r][n] += av[r] * wv[n];
                }
                __syncthreads();
            }
            float* dst = part + (size_t)ks * (NB * ND);
#pragma unroll
            for (int r = 0; r < 8; ++r) {
                float* row = dst + (size_t)(m0 + r0 + r) * ND + c0;
#pragma unroll
                for (int n = 0; n < 5; ++n)
                    *(float2*)(row + n * 2) = *(const float2*)&acc[r][n * 2];
            }
        }
        gbar(&bar[slot++]);

        // ---------------- P2: reduce partials + squash ----------------
        {
            float* dst = (it == 2) ? out : vbuf;
            if (gid < 81920) {
                const int bo = gid >> 4;
                const int sub = gid & 15;
                const int h = sub >> 2, q = sub & 3;
                const float* src = part + (size_t)bo * 16 + q * 4;
                float4 a = { 0, 0, 0, 0 };
#pragma unroll 8
                for (int j = 0; j < 32; ++j) {
                    const float4 p = *(const float4*)(src + (size_t)(h + 4 * j) * (NB * ND));
                    a.x += p.x; a.y += p.y; a.z += p.z; a.w += p.w;
                }
                a.x += __shfl_xor(a.x, 4); a.y += __shfl_xor(a.y, 4);
                a.z += __shfl_xor(a.z, 4); a.w += __shfl_xor(a.w, 4);
                a.x += __shfl_xor(a.x, 8); a.y += __shfl_xor(a.y, 8);
                a.z += __shfl_xor(a.z, 8); a.w += __shfl_xor(a.w, 8);
                float sq = a.x * a.x + a.y * a.y + a.z * a.z + a.w * a.w;
                sq += __shfl_xor(sq, 1);
                sq += __shfl_xor(sq, 2);
                const float f = (sq / (1.0f + sq)) / sqrtf(sq + 1e-8f);
                if (h == 0) {
                    float4 r;
                    r.x = a.x * f; r.y = a.y * f; r.z = a.z * f; r.w = a.w * f;
                    *(float4*)(dst + (size_t)bo * 16 + q * 4) = r;
                }
            }
        }

        if (it < 2) {
            gbar(&bar[slot++]);
            // ---------------- P3: gemm2 + agree (3 tiles per block) ----------------
            {
                const int r0 = rgx * 6;
                const int o0 = c0 >> 4;
                const int nsp = (o0 + 1) * 16 - c0;
                for (int rep = 0; rep < 3; ++rep) {
                    const int vt = bid * 3 + rep;
                    const int kt = vt % P3_NKT;
                    const int bs = vt / P3_NKT;
                    const int k0 = kt * P3_KT, b0 = bs * P3_BCH;
                    if (tid < 120) agr[tid] = 0.f;
                    for (int q = tid; q < 768; q += BLK) {
                        const int bb = q / 24, kv = q - bb * 24;
                        *(float4*)&xl3[bb][kv * 4] =
                            *(const float4*)(x + (size_t)(b0 + bb) * KD + k0 + kv * 4);
                    }
                    for (int q = tid; q < 1280; q += BLK) {
                        const int bb = q / 40, nv = q - bb * 40;
                        *(float4*)&vl3[bb][nv * 4] =
                            *(const float4*)(vbuf + (size_t)(b0 + bb) * ND + nv * 4);
                    }
                    __syncthreads();

                    float acc[6][10] = {};
#pragma unroll 4
                    for (int bb = 0; bb < P3_BCH; ++bb) {
                        const float2 x0 = *(const float2*)&xl3[bb][r0];
                        const float2 x1 = *(const float2*)&xl3[bb][r0 + 2];
                        const float2 x2 = *(const float2*)&xl3[bb][r0 + 4];
                        const float2 w0 = *(const float2*)&vl3[bb][c0 + 0];
                        const float2 w1 = *(const float2*)&vl3[bb][c0 + 2];
                        const float2 w2 = *(const float2*)&vl3[bb][c0 + 4];
                        const float2 w3 = *(const float2*)&vl3[bb][c0 + 6];
                        const float2 w4 = *(const float2*)&vl3[bb][c0 + 8];
                        const float av[6] = { x0.x, x0.y, x1.x, x1.y, x2.x, x2.y };
                        const float wv[10] = { w0.x, w0.y, w1.x, w1.y, w2.x,
                                               w2.y, w3.x, w3.y, w4.x, w4.y };
#pragma unroll
                        for (int r = 0; r < 6; ++r)
#pragma unroll
                            for (int n = 0; n < 10; ++n)
                                acc[r][n] += av[r] * wv[n];
                    }

                    // agree epilogue: contract with Wr, reduce to (i_local, o)
#pragma unroll
                    for (int r = 0; r < 6; ++r) {
                        const int row = r0 + r;
                        const int il = row >> 3;
                        const float* wrow = wrb + (size_t)(k0 + row) * ND + c0;
                        float s0 = 0.f, s1 = 0.f;
#pragma unroll
                        for (int n = 0; n < 10; ++n) {
                            const float t = acc[r][n] * wrow[n];
                            if (n < nsp) s0 += t; else s1 += t;
                        }
                        atomicAdd(&agr[il * 10 + o0], s0);
                        if (nsp < 10) atomicAdd(&agr[il * 10 + o0 + 1], s1);
                    }
                    __syncthreads();
                    if (tid < 120) atomicAdd(&b_ij[kt * 120 + tid], agr[tid] * (1.0f / 512.0f));
                    __syncthreads();
                }
            }
            gbar(&bar[slot++]);
        }
    }
}

extern "C" void kernel_launch(void* const* d_in, const int* in_sizes, int n_in,
                              void* d_out, int out_size, void* d_ws, size_t ws_size,
                              hipStream_t stream)
{
    (void)in_sizes; (void)n_in; (void)out_size; (void)ws_size;
    const float* x = (const float*)d_in[0];
    const float* W = (const float*)d_in[1];
    float* out = (float*)d_out;
    float* ws = (float*)d_ws;

    hipMemsetAsync(ws + 12053760, 0, 16 * sizeof(unsigned), stream); // barrier slots
    digitcaps_mega<<<GRID, BLK, 0, stream>>>(x, W, out, ws);
}

// Round 5
// 691.810 us; speedup vs baseline: 1.3829x; 1.3829x over previous
//
#include <hip/hip_runtime.h>

// DigitCaps dynamic routing, all-f32, single persistent kernel with hand-rolled
// grid barriers. Round-5 fix: barrier polls with RELAXED agent-scope atomic
// loads (sc0/sc1 -> chip-coherent point, NO buffer_inv per poll); acquire is a
// single __threadfence() after spin exit. Round-4's ACQUIRE polling emitted
// buffer_inv every iteration and thrashed all caches (942us, VALU 8%).
// Phases per routing iter:
//   P1 gemm1: part[ks] = x(128 rows) @ (c .* Wr); c computed inline from b_ij
//   P2 reduce 128 partials + squash -> v (or out)
//   P3 gemm2+agree: b_ij += 1/512 * sum W .* (x^T v)   (skip on last iter)
// Wr[(i,s),(o,p)] built once in-kernel (P0); b_ij zeroed in P0.

#define IC 1152
#define OC 10
#define PS 16
#define SS 8
#define NB 512
#define KD 9216
#define ND 160

#define GRID 512
#define BLK 256

#define P1_BM 128
#define P1_KSP 72
#define P1_KC 36

#define P3_KT 96
#define P3_NKT 96
#define P3_BCH 32

__device__ __forceinline__ void gbar(unsigned* slot)
{
    __syncthreads();
    if (threadIdx.x == 0) {
        __threadfence(); // release: write back dirty lines (wbl2)
        __hip_atomic_fetch_add(slot, 1u, __ATOMIC_RELAXED, __HIP_MEMORY_SCOPE_AGENT);
        // RELAXED agent poll: bypasses non-coherent L2, no cache-inv side effect
        while (__hip_atomic_load(slot, __ATOMIC_RELAXED, __HIP_MEMORY_SCOPE_AGENT) < (unsigned)GRID)
            __builtin_amdgcn_s_sleep(8);
        __threadfence(); // acquire: invalidate stale lines once
    }
    __syncthreads();
}

__global__ __launch_bounds__(BLK, 2) void digitcaps_mega(const float* __restrict__ x,
                                                         const float* __restrict__ W,
                                                         float* __restrict__ out,
                                                         float* __restrict__ ws)
{
    // smem union: P1 xl[36][132] (19008B) + wl[36][164] (23616B) + cl[96] (384B)
    //             P3 xl3[32][100] (12800B) + vl3[32][164] (20992B)
    __shared__ __align__(16) char smem[43008];
    __shared__ float agr[120];
    __shared__ float sm[344]; // softmax scratch: maxpart[160], sumpart[160], mo[10]@320, inv[10]@330

    float* b_ij = ws;            // 11520
    float* wrb  = ws + 11520;    // 1474560
    float* part = ws + 1486080;  // 128*81920 = 10485760
    float* vbuf = ws + 11971840; // 81920
    unsigned* bar = (unsigned*)(ws + 12053760); // 16 slots (memset 0 by host)

    const int tid = threadIdx.x;
    const int bid = blockIdx.x;
    const int gid = bid * BLK + tid;
    const int cgx = tid & 15, rgx = tid >> 4;
    const int c0 = cgx * 10;

    float (*xl1)[132] = (float (*)[132])smem;
    float (*wl1)[164] = (float (*)[164])(smem + 19008);
    float* cl         = (float*)(smem + 42624);
    float (*xl3)[100] = (float (*)[100])smem;
    float (*vl3)[164] = (float (*)[164])(smem + 12800);

    int slot = 0;

    // ---------------- P0: zero b_ij, build Wr ----------------
    if (gid < IC * OC) b_ij[gid] = 0.f;
    for (int q = gid; q < (KD * ND) / 4; q += GRID * BLK) {
        const int k = q / 40;
        const int n4 = q - k * 40;
        const int i = k >> 3, s = k & 7;
        const int o = n4 >> 2;
        const int p0 = (n4 << 2) & 15;
        const float* wsrc = W + (((size_t)(i * OC + o) * PS) + p0) * SS + s;
        float4 t;
        t.x = wsrc[0]; t.y = wsrc[SS]; t.z = wsrc[2 * SS]; t.w = wsrc[3 * SS];
        *(float4*)(wrb + (size_t)q * 4) = t;
    }
    gbar(&bar[slot++]);

    for (int it = 0; it < 3; ++it) {
        // ---------------- P1: gemm1 split-K, softmax inline ----------------
        {
            const int mb = bid & 3, ks = bid >> 2;
            const int m0 = mb * P1_BM, k0s = ks * P1_KSP;
            const int r0 = rgx * 8;

            if (it == 0) {
                if (tid < 90) cl[tid] = 1.0f / 1152.0f;
            } else {
                // softmax over i per column o, recomputed per block (b_ij L2-hot)
                if (tid < 160) {
                    const int o = tid % 10, seg = tid / 10;
                    const float* bp = b_ij + o;
                    float m = -3.4e38f;
                    for (int i = seg * 72; i < seg * 72 + 72; ++i)
                        m = fmaxf(m, bp[i * 10]);
                    sm[o * 16 + seg] = m;
                }
                __syncthreads();
                if (tid < 10) {
                    float m = sm[tid * 16];
                    for (int s2 = 1; s2 < 16; ++s2) m = fmaxf(m, sm[tid * 16 + s2]);
                    sm[320 + tid] = m;
                }
                __syncthreads();
                if (tid < 160) {
                    const int o = tid % 10, seg = tid / 10;
                    const float mo = sm[320 + o];
                    const float* bp = b_ij + o;
                    float s = 0.f;
                    for (int i = seg * 72; i < seg * 72 + 72; ++i)
                        s += expf(bp[i * 10] - mo);
                    sm[160 + o * 16 + seg] = s;
                }
                __syncthreads();
                if (tid < 10) {
                    float s = 0.f;
                    for (int s2 = 0; s2 < 16; ++s2) s += sm[160 + tid * 16 + s2];
                    sm[330 + tid] = 1.0f / s;
                }
                __syncthreads();
                if (tid < 90) {
                    const int il = tid / 10, o = tid % 10;
                    const int i = ks * 9 + il;
                    cl[tid] = expf(b_ij[i * 10 + o] - sm[320 + o]) * sm[330 + o];
                }
            }
            __syncthreads();

            float acc[8][10] = {};
            for (int kc = 0; kc < P1_KSP; kc += P1_KC) {
                const int k0 = k0s + kc;
                for (int q = tid; q < 1152; q += BLK) {
                    const int r = q / 9, kv4 = q - r * 9;
                    const float4 t = *(const float4*)(x + (size_t)(m0 + r) * KD + k0 + kv4 * 4);
                    xl1[kv4 * 4 + 0][r] = t.x;
                    xl1[kv4 * 4 + 1][r] = t.y;
                    xl1[kv4 * 4 + 2][r] = t.z;
                    xl1[kv4 * 4 + 3][r] = t.w;
                }
                for (int q = tid; q < 1440; q += BLK) {
                    const int rr = q / 40, c4 = q - rr * 40;
                    float4 t = *(const float4*)(wrb + (size_t)(k0 + rr) * ND + c4 * 4);
                    const float sc = cl[(((kc + rr) >> 3) * 10) + (c4 >> 2)];
                    t.x *= sc; t.y *= sc; t.z *= sc; t.w *= sc;
                    *(float4*)&wl1[rr][c4 * 4] = t;
                }
                __syncthreads();
#pragma unroll 4
                for (int kk = 0; kk < P1_KC; ++kk) {
                    const float4 a0 = *(const float4*)&xl1[kk][r0];
                    const float4 a1 = *(const float4*)&xl1[kk][r0 + 4];
                    const float2 w0 = *(const float2*)&wl1[kk][c0 + 0];
                    const float2 w1 = *(const float2*)&wl1[kk][c0 + 2];
                    const float2 w2 = *(const float2*)&wl1[kk][c0 + 4];
                    const float2 w3 = *(const float2*)&wl1[kk][c0 + 6];
                    const float2 w4 = *(const float2*)&wl1[kk][c0 + 8];
                    const float av[8] = { a0.x, a0.y, a0.z, a0.w, a1.x, a1.y, a1.z, a1.w };
                    const float wv[10] = { w0.x, w0.y, w1.x, w1.y, w2.x,
                                           w2.y, w3.x, w3.y, w4.x, w4.y };
#pragma unroll
                    for (int r = 0; r < 8; ++r)
#pragma unroll
                        for (int n = 0; n < 10; ++n)
                            acc[r][n] += av[r] * wv[n];
                }
                __syncthreads();
            }
            float* dst = part + (size_t)ks * (NB * ND);
#pragma unroll
            for (int r = 0; r < 8; ++r) {
                float* row = dst + (size_t)(m0 + r0 + r) * ND + c0;
#pragma unroll
                for (int n = 0; n < 5; ++n)
                    *(float2*)(row + n * 2) = *(const float2*)&acc[r][n * 2];
            }
        }
        gbar(&bar[slot++]);

        // ---------------- P2: reduce partials + squash ----------------
        {
            float* dst = (it == 2) ? out : vbuf;
            if (gid < 81920) {
                const int bo = gid >> 4;
                const int sub = gid & 15;
                const int h = sub >> 2, q = sub & 3;
                const float* src = part + (size_t)bo * 16 + q * 4;
                float4 a = { 0, 0, 0, 0 };
#pragma unroll 8
                for (int j = 0; j < 32; ++j) {
                    const float4 p = *(const float4*)(src + (size_t)(h + 4 * j) * (NB * ND));
                    a.x += p.x; a.y += p.y; a.z += p.z; a.w += p.w;
                }
                a.x += __shfl_xor(a.x, 4); a.y += __shfl_xor(a.y, 4);
                a.z += __shfl_xor(a.z, 4); a.w += __shfl_xor(a.w, 4);
                a.x += __shfl_xor(a.x, 8); a.y += __shfl_xor(a.y, 8);
                a.z += __shfl_xor(a.z, 8); a.w += __shfl_xor(a.w, 8);
                float sq = a.x * a.x + a.y * a.y + a.z * a.z + a.w * a.w;
                sq += __shfl_xor(sq, 1);
                sq += __shfl_xor(sq, 2);
                const float f = (sq / (1.0f + sq)) / sqrtf(sq + 1e-8f);
                if (h == 0) {
                    float4 r;
                    r.x = a.x * f; r.y = a.y * f; r.z = a.z * f; r.w = a.w * f;
                    *(float4*)(dst + (size_t)bo * 16 + q * 4) = r;
                }
            }
        }

        if (it < 2) {
            gbar(&bar[slot++]);
            // ---------------- P3: gemm2 + agree (3 tiles per block) ----------------
            {
                const int r0 = rgx * 6;
                const int o0 = c0 >> 4;
                const int nsp = (o0 + 1) * 16 - c0;
                for (int rep = 0; rep < 3; ++rep) {
                    const int vt = bid * 3 + rep;
                    const int kt = vt % P3_NKT;
                    const int bs = vt / P3_NKT;
                    const int k0 = kt * P3_KT, b0 = bs * P3_BCH;
                    if (tid < 120) agr[tid] = 0.f;
                    for (int q = tid; q < 768; q += BLK) {
                        const int bb = q / 24, kv = q - bb * 24;
                        *(float4*)&xl3[bb][kv * 4] =
                            *(const float4*)(x + (size_t)(b0 + bb) * KD + k0 + kv * 4);
                    }
                    for (int q = tid; q < 1280; q += BLK) {
                        const int bb = q / 40, nv = q - bb * 40;
                        *(float4*)&vl3[bb][nv * 4] =
                            *(const float4*)(vbuf + (size_t)(b0 + bb) * ND + nv * 4);
                    }
                    __syncthreads();

                    float acc[6][10] = {};
#pragma unroll 4
                    for (int bb = 0; bb < P3_BCH; ++bb) {
                        const float2 x0 = *(const float2*)&xl3[bb][r0];
                        const float2 x1 = *(const float2*)&xl3[bb][r0 + 2];
                        const float2 x2 = *(const float2*)&xl3[bb][r0 + 4];
                        const float2 w0 = *(const float2*)&vl3[bb][c0 + 0];
                        const float2 w1 = *(const float2*)&vl3[bb][c0 + 2];
                        const float2 w2 = *(const float2*)&vl3[bb][c0 + 4];
                        const float2 w3 = *(const float2*)&vl3[bb][c0 + 6];
                        const float2 w4 = *(const float2*)&vl3[bb][c0 + 8];
                        const float av[6] = { x0.x, x0.y, x1.x, x1.y, x2.x, x2.y };
                        const float wv[10] = { w0.x, w0.y, w1.x, w1.y, w2.x,
                                               w2.y, w3.x, w3.y, w4.x, w4.y };
#pragma unroll
                        for (int r = 0; r < 6; ++r)
#pragma unroll
                            for (int n = 0; n < 10; ++n)
                                acc[r][n] += av[r] * wv[n];
                    }

                    // agree epilogue: contract with Wr, reduce to (i_local, o)
#pragma unroll
                    for (int r = 0; r < 6; ++r) {
                        const int row = r0 + r;
                        const int il = row >> 3;
                        const float* wrow = wrb + (size_t)(k0 + row) * ND + c0;
                        float s0 = 0.f, s1 = 0.f;
#pragma unroll
                        for (int n = 0; n < 10; ++n) {
                            const float t = acc[r][n] * wrow[n];
                            if (n < nsp) s0 += t; else s1 += t;
                        }
                        atomicAdd(&agr[il * 10 + o0], s0);
                        if (nsp < 10) atomicAdd(&agr[il * 10 + o0 + 1], s1);
                    }
                    __syncthreads();
                    if (tid < 120) atomicAdd(&b_ij[kt * 120 + tid], agr[tid] * (1.0f / 512.0f));
                    __syncthreads();
                }
            }
            gbar(&bar[slot++]);
        }
    }
}

extern "C" void kernel_launch(void* const* d_in, const int* in_sizes, int n_in,
                              void* d_out, int out_size, void* d_ws, size_t ws_size,
                              hipStream_t stream)
{
    (void)in_sizes; (void)n_in; (void)out_size; (void)ws_size;
    const float* x = (const float*)d_in[0];
    const float* W = (const float*)d_in[1];
    float* out = (float*)d_out;
    float* ws = (float*)d_ws;

    hipMemsetAsync(ws + 12053760, 0, 16 * sizeof(unsigned), stream); // barrier slots
    digitcaps_mega<<<GRID, BLK, 0, stream>>>(x, W, out, ws);
}

// Round 7
// 597.461 us; speedup vs baseline: 1.6012x; 1.1579x over previous
//
#include <hip/hip_runtime.h>

// DigitCaps dynamic routing, all-f32, single persistent kernel.
// Round-6 barrier design: NO per-block __threadfence (round-4/5 paid a
// buffer_wbl2 dirty-L2 walk per block per barrier -> fence storm).
// Instead: all cross-phase producer stores are RELAXED AGENT atomic stores
// (global_store sc1: write-through past the non-coherent XCD L2 to the
// chip-coherent point). Barrier = waitcnt drain + relaxed arrive + relaxed
// poll + ONE acquire load (single flash buffer_inv, no dirty walk).
// Phases per routing iter:
//   P1 gemm1: part[ks] = x(128 rows) @ (c .* Wr); c computed inline from b_ij
//   P2 reduce 128 partials + squash -> v (or out; out via normal stores)
//   P3 gemm2+agree: b_ij += 1/512 * sum W .* (x^T v)   (skip on last iter)
// Wr built once in P0; b_ij zeroed in P0.

#define IC 1152
#define OC 10
#define PS 16
#define SS 8
#define NB 512
#define KD 9216
#define ND 160

#define GRID 512
#define BLK 256

#define P1_BM 128
#define P1_KSP 72
#define P1_KC 36

#define P3_KT 96
#define P3_NKT 96
#define P3_BCH 32

// write-through (agent-coherent) 8-byte store: two f32 -> global_store sc1
__device__ __forceinline__ void st_agent2(float* p, float a, float b)
{
    unsigned long long u = (unsigned long long)__float_as_uint(a) |
                           ((unsigned long long)__float_as_uint(b) << 32);
    __hip_atomic_store((unsigned long long*)p, u, __ATOMIC_RELAXED,
                       __HIP_MEMORY_SCOPE_AGENT);
}

__device__ __forceinline__ void gbar(unsigned* slot)
{
    // drain this wave's sc1 stores to the coherent point (no cache writeback
    // needed: nothing cross-phase is dirty in L2)
    asm volatile("s_waitcnt vmcnt(0) lgkmcnt(0)" ::: "memory");
    __syncthreads();
    if (threadIdx.x == 0) {
        __hip_atomic_fetch_add(slot, 1u, __ATOMIC_RELAXED, __HIP_MEMORY_SCOPE_AGENT);
        while (__hip_atomic_load(slot, __ATOMIC_RELAXED, __HIP_MEMORY_SCOPE_AGENT) < (unsigned)GRID)
            __builtin_amdgcn_s_sleep(2);
        // single acquire: one flash invalidate of (clean) L1/L2 lines
        (void)__hip_atomic_load(slot, __ATOMIC_ACQUIRE, __HIP_MEMORY_SCOPE_AGENT);
    }
    __syncthreads();
}

__global__ __launch_bounds__(BLK, 2) void digitcaps_mega(const float* __restrict__ x,
                                                         const float* __restrict__ W,
                                                         float* __restrict__ out,
                                                         float* __restrict__ ws)
{
    // smem union: P1 xl[36][132] (19008B) + wl[36][164] (23616B) + cl[96]
    //             P3 xl3[32][100] (12800B) + vl3[32][164] (20992B)
    __shared__ __align__(16) char smem[43008];
    __shared__ float agr[120];
    __shared__ float sm[344]; // maxpart[160], sumpart[160], mo[10]@320, inv[10]@330

    float* b_ij = ws;            // 11520
    float* wrb  = ws + 11520;    // 1474560
    float* part = ws + 1486080;  // 128*81920 = 10485760
    float* vbuf = ws + 11971840; // 81920
    unsigned* bar = (unsigned*)(ws + 12053760); // 16 slots (memset 0 by host)

    const int tid = threadIdx.x;
    const int bid = blockIdx.x;
    const int gid = bid * BLK + tid;
    const int cgx = tid & 15, rgx = tid >> 4;
    const int c0 = cgx * 10;

    float (*xl1)[132] = (float (*)[132])smem;
    float (*wl1)[164] = (float (*)[164])(smem + 19008);
    float* cl         = (float*)(smem + 42624);
    float (*xl3)[100] = (float (*)[100])smem;
    float (*vl3)[164] = (float (*)[164])(smem + 12800);

    int slot = 0;

    // ---------------- P0: zero b_ij, build Wr (sc1 stores) ----------------
    if (gid < IC * OC)
        __hip_atomic_store((unsigned*)&b_ij[gid], 0u, __ATOMIC_RELAXED,
                           __HIP_MEMORY_SCOPE_AGENT);
    for (int q = gid; q < (KD * ND) / 4; q += GRID * BLK) {
        const int k = q / 40;
        const int n4 = q - k * 40;
        const int i = k >> 3, s = k & 7;
        const int o = n4 >> 2;
        const int p0 = (n4 << 2) & 15;
        const float* wsrc = W + (((size_t)(i * OC + o) * PS) + p0) * SS + s;
        float* dst = wrb + (size_t)q * 4;
        st_agent2(dst + 0, wsrc[0], wsrc[SS]);
        st_agent2(dst + 2, wsrc[2 * SS], wsrc[3 * SS]);
    }
    gbar(&bar[slot++]);

    for (int it = 0; it < 3; ++it) {
        // ---------------- P1: gemm1 split-K, softmax inline ----------------
        {
            const int mb = bid & 3, ks = bid >> 2;
            const int m0 = mb * P1_BM, k0s = ks * P1_KSP;
            const int r0 = rgx * 8;

            if (it == 0) {
                if (tid < 90) cl[tid] = 1.0f / 1152.0f;
            } else {
                // softmax over i per column o, recomputed per block
                if (tid < 160) {
                    const int o = tid % 10, seg = tid / 10;
                    const float* bp = b_ij + o;
                    float m = -3.4e38f;
                    for (int i = seg * 72; i < seg * 72 + 72; ++i)
                        m = fmaxf(m, bp[i * 10]);
                    sm[o * 16 + seg] = m;
                }
                __syncthreads();
                if (tid < 10) {
                    float m = sm[tid * 16];
                    for (int s2 = 1; s2 < 16; ++s2) m = fmaxf(m, sm[tid * 16 + s2]);
                    sm[320 + tid] = m;
                }
                __syncthreads();
                if (tid < 160) {
                    const int o = tid % 10, seg = tid / 10;
                    const float mo = sm[320 + o];
                    const float* bp = b_ij + o;
                    float s = 0.f;
                    for (int i = seg * 72; i < seg * 72 + 72; ++i)
                        s += expf(bp[i * 10] - mo);
                    sm[160 + o * 16 + seg] = s;
                }
                __syncthreads();
                if (tid < 10) {
                    float s = 0.f;
                    for (int s2 = 0; s2 < 16; ++s2) s += sm[160 + tid * 16 + s2];
                    sm[330 + tid] = 1.0f / s;
                }
                __syncthreads();
                if (tid < 90) {
                    const int il = tid / 10, o = tid % 10;
                    const int i = ks * 9 + il;
                    cl[tid] = expf(b_ij[i * 10 + o] - sm[320 + o]) * sm[330 + o];
                }
            }
            __syncthreads();

            float acc[8][10] = {};
            for (int kc = 0; kc < P1_KSP; kc += P1_KC) {
                const int k0 = k0s + kc;
                for (int q = tid; q < 1152; q += BLK) {
                    const int r = q / 9, kv4 = q - r * 9;
                    const float4 t = *(const float4*)(x + (size_t)(m0 + r) * KD + k0 + kv4 * 4);
                    xl1[kv4 * 4 + 0][r] = t.x;
                    xl1[kv4 * 4 + 1][r] = t.y;
                    xl1[kv4 * 4 + 2][r] = t.z;
                    xl1[kv4 * 4 + 3][r] = t.w;
                }
                for (int q = tid; q < 1440; q += BLK) {
                    const int rr = q / 40, c4 = q - rr * 40;
                    float4 t = *(const float4*)(wrb + (size_t)(k0 + rr) * ND + c4 * 4);
                    const float sc = cl[(((kc + rr) >> 3) * 10) + (c4 >> 2)];
                    t.x *= sc; t.y *= sc; t.z *= sc; t.w *= sc;
                    *(float4*)&wl1[rr][c4 * 4] = t;
                }
                __syncthreads();
#pragma unroll 4
                for (int kk = 0; kk < P1_KC; ++kk) {
                    const float4 a0 = *(const float4*)&xl1[kk][r0];
                    const float4 a1 = *(const float4*)&xl1[kk][r0 + 4];
                    const float2 w0 = *(const float2*)&wl1[kk][c0 + 0];
                    const float2 w1 = *(const float2*)&wl1[kk][c0 + 2];
                    const float2 w2 = *(const float2*)&wl1[kk][c0 + 4];
                    const float2 w3 = *(const float2*)&wl1[kk][c0 + 6];
                    const float2 w4 = *(const float2*)&wl1[kk][c0 + 8];
                    const float av[8] = { a0.x, a0.y, a0.z, a0.w, a1.x, a1.y, a1.z, a1.w };
                    const float wv[10] = { w0.x, w0.y, w1.x, w1.y, w2.x,
                                           w2.y, w3.x, w3.y, w4.x, w4.y };
#pragma unroll
                    for (int r = 0; r < 8; ++r)
#pragma unroll
                        for (int n = 0; n < 10; ++n)
                            acc[r][n] += av[r] * wv[n];
                }
                __syncthreads();
            }
            float* dst = part + (size_t)ks * (NB * ND);
#pragma unroll
            for (int r = 0; r < 8; ++r) {
                float* row = dst + (size_t)(m0 + r0 + r) * ND + c0;
#pragma unroll
                for (int n = 0; n < 5; ++n)
                    st_agent2(row + n * 2, acc[r][n * 2], acc[r][n * 2 + 1]);
            }
        }
        gbar(&bar[slot++]);

        // ---------------- P2: reduce partials + squash ----------------
        {
            if (gid < 81920) {
                const int bo = gid >> 4;
                const int sub = gid & 15;
                const int h = sub >> 2, q = sub & 3;
                const float* src = part + (size_t)bo * 16 + q * 4;
                float4 a = { 0, 0, 0, 0 };
#pragma unroll 8
                for (int j = 0; j < 32; ++j) {
                    const float4 p = *(const float4*)(src + (size_t)(h + 4 * j) * (NB * ND));
                    a.x += p.x; a.y += p.y; a.z += p.z; a.w += p.w;
                }
                a.x += __shfl_xor(a.x, 4); a.y += __shfl_xor(a.y, 4);
                a.z += __shfl_xor(a.z, 4); a.w += __shfl_xor(a.w, 4);
                a.x += __shfl_xor(a.x, 8); a.y += __shfl_xor(a.y, 8);
                a.z += __shfl_xor(a.z, 8); a.w += __shfl_xor(a.w, 8);
                float sq = a.x * a.x + a.y * a.y + a.z * a.z + a.w * a.w;
                sq += __shfl_xor(sq, 1);
                sq += __shfl_xor(sq, 2);
                const float f = (sq / (1.0f + sq)) / sqrtf(sq + 1e-8f);
                if (h == 0) {
                    if (it == 2) {
                        float4 r;
                        r.x = a.x * f; r.y = a.y * f; r.z = a.z * f; r.w = a.w * f;
                        *(float4*)(out + (size_t)bo * 16 + q * 4) = r; // normal store: kernel-end flush
                    } else {
                        float* vp = vbuf + (size_t)bo * 16 + q * 4;
                        st_agent2(vp + 0, a.x * f, a.y * f);
                        st_agent2(vp + 2, a.z * f, a.w * f);
                    }
                }
            }
        }

        if (it < 2) {
            gbar(&bar[slot++]);
            // ---------------- P3: gemm2 + agree (3 tiles per block) ----------------
            {
                const int r0 = rgx * 6;
                const int o0 = c0 >> 4;
                const int nsp = (o0 + 1) * 16 - c0;
                for (int rep = 0; rep < 3; ++rep) {
                    const int vt = bid * 3 + rep;
                    const int kt = vt % P3_NKT;
                    const int bs = vt / P3_NKT;
                    const int k0 = kt * P3_KT, b0 = bs * P3_BCH;
                    if (tid < 120) agr[tid] = 0.f;
                    for (int q = tid; q < 768; q += BLK) {
                        const int bb = q / 24, kv = q - bb * 24;
                        *(float4*)&xl3[bb][kv * 4] =
                            *(const float4*)(x + (size_t)(b0 + bb) * KD + k0 + kv * 4);
                    }
                    for (int q = tid; q < 1280; q += BLK) {
                        const int bb = q / 40, nv = q - bb * 40;
                        *(float4*)&vl3[bb][nv * 4] =
                            *(const float4*)(vbuf + (size_t)(b0 + bb) * ND + nv * 4);
                    }
                    __syncthreads();

                    float acc[6][10] = {};
#pragma unroll 4
                    for (int bb = 0; bb < P3_BCH; ++bb) {
                        const float2 x0 = *(const float2*)&xl3[bb][r0];
                        const float2 x1 = *(const float2*)&xl3[bb][r0 + 2];
                        const float2 x2 = *(const float2*)&xl3[bb][r0 + 4];
                        const float2 w0 = *(const float2*)&vl3[bb][c0 + 0];
                        const float2 w1 = *(const float2*)&vl3[bb][c0 + 2];
                        const float2 w2 = *(const float2*)&vl3[bb][c0 + 4];
                        const float2 w3 = *(const float2*)&vl3[bb][c0 + 6];
                        const float2 w4 = *(const float2*)&vl3[bb][c0 + 8];
                        const float av[6] = { x0.x, x0.y, x1.x, x1.y, x2.x, x2.y };
                        const float wv[10] = { w0.x, w0.y, w1.x, w1.y, w2.x,
                                               w2.y, w3.x, w3.y, w4.x, w4.y };
#pragma unroll
                        for (int r = 0; r < 6; ++r)
#pragma unroll
                            for (int n = 0; n < 10; ++n)
                                acc[r][n] += av[r] * wv[n];
                    }

                    // agree epilogue: contract with Wr, reduce to (i_local, o)
#pragma unroll
                    for (int r = 0; r < 6; ++r) {
                        const int row = r0 + r;
                        const int il = row >> 3;
                        const float* wrow = wrb + (size_t)(k0 + row) * ND + c0;
                        float s0 = 0.f, s1 = 0.f;
#pragma unroll
                        for (int n = 0; n < 10; ++n) {
                            const float t = acc[r][n] * wrow[n];
                            if (n < nsp) s0 += t; else s1 += t;
                        }
                        atomicAdd(&agr[il * 10 + o0], s0);
                        if (nsp < 10) atomicAdd(&agr[il * 10 + o0 + 1], s1);
                    }
                    __syncthreads();
                    if (tid < 120) atomicAdd(&b_ij[kt * 120 + tid], agr[tid] * (1.0f / 512.0f));
                    __syncthreads();
                }
            }
            gbar(&bar[slot++]);
        }
    }
}

extern "C" void kernel_launch(void* const* d_in, const int* in_sizes, int n_in,
                              void* d_out, int out_size, void* d_ws, size_t ws_size,
                              hipStream_t stream)
{
    (void)in_sizes; (void)n_in; (void)out_size; (void)ws_size;
    const float* x = (const float*)d_in[0];
    const float* W = (const float*)d_in[1];
    float* out = (float*)d_out;
    float* ws = (float*)d_ws;

    hipMemsetAsync(ws + 12053760, 0, 16 * sizeof(unsigned), stream); // barrier slots
    digitcaps_mega<<<GRID, BLK, 0, stream>>>(x, W, out, ws);
}

// Round 9
// 277.103 us; speedup vs baseline: 3.4524x; 2.1561x over previous
//
#include <hip/hip_runtime.h>

// DigitCaps dynamic routing, all-f32. Multi-kernel (stream-ordered) — the
// persistent-barrier experiments (r4-r7) lost to kernel-boundary flushes:
// acquire-poll thrashed caches (942us), threadfence dirty-walk storm (692us),
// sc1 write-through pushed 506MB to HBM (597us). Multi-kernel r2 = 264us.
// This round: same proven compute tiles, 9 dispatches instead of 12:
//   prep_wr zeroes b_ij (no memset); softmax recomputed per-block inside
//   gemm1_fused (no softmax dispatches); reduce_squash 4x wider (mega P2).
// Per iter: gemm1(512blk) -> reduce(320blk) -> gemm2_agree(2304blk, skip last)

#define IC 1152
#define OC 10
#define PS 16
#define SS 8
#define NB 512
#define KD 9216
#define ND 160

#define G1_NS 128
#define G1_BM 128
#define G1_KSP 72
#define G1_KC 36

#define G2_BCH 32
#define G2_NBS 16
#define G2_NKT 144

// ---------------- Wr[(i*8+s)*160 + (o*16+p)] = W[i,o,p,s]; zero b_ij --------
__global__ void prep_wr(const float* __restrict__ W, float* __restrict__ wr,
                        float* __restrict__ bij)
{
    const int q = blockIdx.x * 256 + threadIdx.x; // float4 index, 368640 total
    if (q < IC * OC) bij[q] = 0.f;
    const int k = q / 40;
    const int n4 = q - k * 40;
    const int i = k >> 3, s = k & 7;
    const int o = n4 >> 2;
    const int p0 = (n4 << 2) & 15;
    const float* wsrc = W + (((size_t)(i * OC + o) * PS) + p0) * SS + s;
    float4 t;
    t.x = wsrc[0]; t.y = wsrc[SS]; t.z = wsrc[2 * SS]; t.w = wsrc[3 * SS];
    *(float4*)(wr + (size_t)q * 4) = t;
}

// ---------------- GEMM1: part[ks] = x[128 rows] @ (softmax(b) .* Wr) ---------
__global__ __launch_bounds__(256, 2) void gemm1_fused(const float* __restrict__ x,
                                                      const float* __restrict__ wr,
                                                      const float* __restrict__ bij,
                                                      float* __restrict__ part,
                                                      int it)
{
    __shared__ __align__(16) float xl[G1_KC][G1_BM + 4]; // [k][row]
    __shared__ __align__(16) float wl[G1_KC][ND + 4];    // [k][n]
    __shared__ float cl[96];
    __shared__ float sm[344]; // maxpart[160], sumpart[160], mo[10]@320, inv[10]@330

    const int tid = threadIdx.x;
    const int mb = blockIdx.x & 3;  // 4 m-tiles of 128 rows
    const int ks = blockIdx.x >> 2; // 128 K-splits of 72
    const int m0 = mb * G1_BM;
    const int k0s = ks * G1_KSP;
    const int cg = tid & 15, rg = tid >> 4;
    const int c0 = cg * 10, r0 = rg * 8;

    // c-slice for this split (i in [ks*9, ks*9+9)), softmax over i per o,
    // recomputed per block from b_ij (46KB, L2-hot; verified in mega r4-r7)
    if (it == 0) {
        if (tid < 90) cl[tid] = 1.0f / 1152.0f;
    } else {
        if (tid < 160) {
            const int o = tid % 10, seg = tid / 10;
            const float* bp = bij + o;
            float m = -3.4e38f;
            for (int i = seg * 72; i < seg * 72 + 72; ++i)
                m = fmaxf(m, bp[i * 10]);
            sm[o * 16 + seg] = m;
        }
        __syncthreads();
        if (tid < 10) {
            float m = sm[tid * 16];
            for (int s2 = 1; s2 < 16; ++s2) m = fmaxf(m, sm[tid * 16 + s2]);
            sm[320 + tid] = m;
        }
        __syncthreads();
        if (tid < 160) {
            const int o = tid % 10, seg = tid / 10;
            const float mo = sm[320 + o];
            const float* bp = bij + o;
            float s = 0.f;
            for (int i = seg * 72; i < seg * 72 + 72; ++i)
                s += expf(bp[i * 10] - mo);
            sm[160 + o * 16 + seg] = s;
        }
        __syncthreads();
        if (tid < 10) {
            float s = 0.f;
            for (int s2 = 0; s2 < 16; ++s2) s += sm[160 + tid * 16 + s2];
            sm[330 + tid] = 1.0f / s;
        }
        __syncthreads();
        if (tid < 90) {
            const int il = tid / 10, o = tid % 10;
            const int i = ks * 9 + il;
            cl[tid] = expf(bij[i * 10 + o] - sm[320 + o]) * sm[330 + o];
        }
    }
    __syncthreads();

    float acc[8][10] = {};

    for (int kc = 0; kc < G1_KSP; kc += G1_KC) {
        const int k0 = k0s + kc;
        // stage x tile transposed: 128 rows x 36 k
        for (int q = tid; q < 1152; q += 256) {
            const int r = q / 9, kv4 = q - r * 9;
            const float4 t = *(const float4*)(x + (size_t)(m0 + r) * KD + k0 + kv4 * 4);
            xl[kv4 * 4 + 0][r] = t.x;
            xl[kv4 * 4 + 1][r] = t.y;
            xl[kv4 * 4 + 2][r] = t.z;
            xl[kv4 * 4 + 3][r] = t.w;
        }
        // stage (c .* Wr) tile: 36 k x 160 n
        for (int q = tid; q < 1440; q += 256) {
            const int rr = q / 40, c4 = q - rr * 40;
            float4 t = *(const float4*)(wr + (size_t)(k0 + rr) * ND + c4 * 4);
            const float sc = cl[(((kc + rr) >> 3) * 10) + (c4 >> 2)];
            t.x *= sc; t.y *= sc; t.z *= sc; t.w *= sc;
            *(float4*)&wl[rr][c4 * 4] = t;
        }
        __syncthreads();
#pragma unroll 4
        for (int kk = 0; kk < G1_KC; ++kk) {
            const float4 a0 = *(const float4*)&xl[kk][r0];
            const float4 a1 = *(const float4*)&xl[kk][r0 + 4];
            const float2 w0 = *(const float2*)&wl[kk][c0 + 0];
            const float2 w1 = *(const float2*)&wl[kk][c0 + 2];
            const float2 w2 = *(const float2*)&wl[kk][c0 + 4];
            const float2 w3 = *(const float2*)&wl[kk][c0 + 6];
            const float2 w4 = *(const float2*)&wl[kk][c0 + 8];
            const float av[8] = { a0.x, a0.y, a0.z, a0.w, a1.x, a1.y, a1.z, a1.w };
            const float wv[10] = { w0.x, w0.y, w1.x, w1.y, w2.x,
                                   w2.y, w3.x, w3.y, w4.x, w4.y };
#pragma unroll
            for (int r = 0; r < 8; ++r)
#pragma unroll
                for (int n = 0; n < 10; ++n)
                    acc[r][n] += av[r] * wv[n];
        }
        __syncthreads();
    }

    float* dst = part + (size_t)ks * (NB * ND);
#pragma unroll
    for (int r = 0; r < 8; ++r) {
        float* row = dst + (size_t)(m0 + r0 + r) * ND + c0;
#pragma unroll
        for (int n = 0; n < 5; ++n)
            *(float2*)(row + n * 2) = *(const float2*)&acc[r][n * 2];
    }
}

// ---------------- reduce split-K partials + squash (mega P2, 4-way) ----------
__global__ void reduce_squash(const float* __restrict__ part, float* __restrict__ out)
{
    const int gid = blockIdx.x * 256 + threadIdx.x; // 81920 = 512*10*16
    const int bo = gid >> 4;
    const int sub = gid & 15;
    const int h = sub >> 2, q = sub & 3;
    const float* src = part + (size_t)bo * 16 + q * 4;
    float4 a = { 0, 0, 0, 0 };
#pragma unroll 8
    for (int j = 0; j < 32; ++j) {
        const float4 p = *(const float4*)(src + (size_t)(h + 4 * j) * (NB * ND));
        a.x += p.x; a.y += p.y; a.z += p.z; a.w += p.w;
    }
    a.x += __shfl_xor(a.x, 4); a.y += __shfl_xor(a.y, 4);
    a.z += __shfl_xor(a.z, 4); a.w += __shfl_xor(a.w, 4);
    a.x += __shfl_xor(a.x, 8); a.y += __shfl_xor(a.y, 8);
    a.z += __shfl_xor(a.z, 8); a.w += __shfl_xor(a.w, 8);
    float sq = a.x * a.x + a.y * a.y + a.z * a.z + a.w * a.w;
    sq += __shfl_xor(sq, 1);
    sq += __shfl_xor(sq, 2);
    const float f = (sq / (1.0f + sq)) / sqrtf(sq + 1e-8f);
    if (h == 0) {
        float4 r;
        r.x = a.x * f; r.y = a.y * f; r.z = a.z * f; r.w = a.w * f;
        *(float4*)(out + (size_t)bo * 16 + q * 4) = r;
    }
}

// ---------------- GEMM2+agree: b_ij += (1/512) sum W .* (x^T v) --------------
__global__ __launch_bounds__(128, 2) void gemm2_agree(const float* __restrict__ x,
                                                      const float* __restrict__ v,
                                                      const float* __restrict__ wr,
                                                      float* __restrict__ bij)
{
    __shared__ __align__(16) float xl[G2_BCH][68];  // [batch][k (64)]
    __shared__ __align__(16) float vl[G2_BCH][164]; // [batch][n (160)]
    __shared__ float agr[80];

    const int tid = threadIdx.x;
    const int kt = blockIdx.x % G2_NKT; // 144 k-tiles of 64
    const int bs = blockIdx.x / G2_NKT; // 16 batch chunks of 32
    const int k0 = kt * 64, b0 = bs * G2_BCH;
    const int cg = tid & 15, rg = tid >> 4; // rg 0..7
    const int c0 = cg * 10, r0 = rg * 8;

    if (tid < 80) agr[tid] = 0.f;

    for (int q = tid; q < G2_BCH * 16; q += 128) { // 512
        const int bb = q >> 4, kv = q & 15;
        *(float4*)&xl[bb][kv * 4] = *(const float4*)(x + (size_t)(b0 + bb) * KD + k0 + kv * 4);
    }
    for (int q = tid; q < G2_BCH * 40; q += 128) { // 1280
        const int bb = q / 40, nv = q - bb * 40;
        *(float4*)&vl[bb][nv * 4] = *(const float4*)(v + (size_t)(b0 + bb) * ND + nv * 4);
    }
    __syncthreads();

    float acc[8][10] = {};
#pragma unroll 4
    for (int bb = 0; bb < G2_BCH; ++bb) {
        const float4 a0 = *(const float4*)&xl[bb][r0];
        const float4 a1 = *(const float4*)&xl[bb][r0 + 4];
        const float2 w0 = *(const float2*)&vl[bb][c0 + 0];
        const float2 w1 = *(const float2*)&vl[bb][c0 + 2];
        const float2 w2 = *(const float2*)&vl[bb][c0 + 4];
        const float2 w3 = *(const float2*)&vl[bb][c0 + 6];
        const float2 w4 = *(const float2*)&vl[bb][c0 + 8];
        const float av[8] = { a0.x, a0.y, a0.z, a0.w, a1.x, a1.y, a1.z, a1.w };
        const float wv[10] = { w0.x, w0.y, w1.x, w1.y, w2.x,
                               w2.y, w3.x, w3.y, w4.x, w4.y };
#pragma unroll
        for (int r = 0; r < 8; ++r)
#pragma unroll
            for (int n = 0; n < 10; ++n)
                acc[r][n] += av[r] * wv[n];
    }

    // epilogue: contract G-tile with Wr, reduce to (i_local=rg, o) pairs
    const int o0 = c0 >> 4;
    const int nsp = (o0 + 1) * 16 - c0; // 1..16: first cols belong to o0
    float sum0 = 0.f, sum1 = 0.f;
#pragma unroll
    for (int r = 0; r < 8; ++r) {
        const float* wrow = wr + (size_t)(k0 + r0 + r) * ND + c0;
#pragma unroll
        for (int n = 0; n < 10; ++n) {
            const float t = acc[r][n] * wrow[n];
            if (n < nsp) sum0 += t; else sum1 += t;
        }
    }
    atomicAdd(&agr[rg * 10 + o0], sum0);
    if (nsp < 10) atomicAdd(&agr[rg * 10 + o0 + 1], sum1);
    __syncthreads();

    if (tid < 80) atomicAdd(bij + kt * 80 + tid, agr[tid] * (1.0f / 512.0f));
}

extern "C" void kernel_launch(void* const* d_in, const int* in_sizes, int n_in,
                              void* d_out, int out_size, void* d_ws, size_t ws_size,
                              hipStream_t stream)
{
    (void)in_sizes; (void)n_in; (void)out_size; (void)ws_size;
    const float* x = (const float*)d_in[0];
    const float* W = (const float*)d_in[1];
    float* out = (float*)d_out;
    float* ws = (float*)d_ws;

    // ws layout (floats)
    float* b_ij = ws;            // 11520
    float* wrb  = ws + 11520;    // 1474560
    float* part = ws + 1486080;  // 128*81920 = 10485760
    float* vbuf = ws + 11971840; // 81920

    prep_wr<<<1440, 256, 0, stream>>>(W, wrb, b_ij);

    for (int it = 0; it < 3; ++it) {
        gemm1_fused<<<G1_NS * 4, 256, 0, stream>>>(x, wrb, b_ij, part, it);
        reduce_squash<<<320, 256, 0, stream>>>(part, (it == 2) ? out : vbuf);
        if (it < 2)
            gemm2_agree<<<G2_NKT * G2_NBS, 128, 0, stream>>>(x, vbuf, wrb, b_ij);
    }
}